// Round 3
// baseline (675.422 us; speedup 1.0000x reference)
//
#include <hip/hip_runtime.h>
#include <hip/hip_bf16.h>

typedef unsigned int uint32_ty;

// native vector types for nontemporal builtins (HIP_vector_type not accepted)
typedef float  nfloat2 __attribute__((ext_vector_type(2)));
typedef float  nfloat4 __attribute__((ext_vector_type(4)));
typedef int    nint4   __attribute__((ext_vector_type(4)));

// Problem constants
#define BB 4
#define SS 512
#define DD 768
#define HH 12
#define DHH 64
#define SDD 30

// padded LDS row stride (elements) for bf16 rows of length 512
#define LP 520

__device__ __forceinline__ float bfu(unsigned short u) {
    return __uint_as_float(((uint32_ty)u) << 16);
}
__device__ __forceinline__ unsigned short tobf(float f) {
    return __bfloat16_as_ushort(__float2bfloat16(f));
}
__device__ __forceinline__ void unp8(uint4 u, float* t) {
    t[0] = __uint_as_float(u.x << 16);
    t[1] = __uint_as_float(u.x & 0xFFFF0000u);
    t[2] = __uint_as_float(u.y << 16);
    t[3] = __uint_as_float(u.y & 0xFFFF0000u);
    t[4] = __uint_as_float(u.z << 16);
    t[5] = __uint_as_float(u.z & 0xFFFF0000u);
    t[6] = __uint_as_float(u.w << 16);
    t[7] = __uint_as_float(u.w & 0xFFFF0000u);
}

// ---------------------------------------------------------------------------
// GEMM tiles: BM=128, BN=64, BK=16, 256 threads, 8x4 per-thread microtile.
// FMA:LDS-read = 32:3 per kk; 24.6k FMA/thread over K=768.
// ---------------------------------------------------------------------------
#define GBM 128
#define GBN 64
#define GBK 16

// K1: fused projection GEMMs.  blockIdx.z selects {query,key,value}.
// z=0 -> q (B,H,S,DH) scaled 1/8; z=1 -> kT (B,H,DH,S); z=2 -> v (B,H,S,DH).
__global__ __launch_bounds__(256) void gemm_proj3(
    const float* __restrict__ Xq, const float* __restrict__ Xk, const float* __restrict__ Xv,
    const float* __restrict__ Wq, const float* __restrict__ Wk, const float* __restrict__ Wv,
    const float* __restrict__ bq, const float* __restrict__ bk, const float* __restrict__ bv,
    float* __restrict__ oq, float* __restrict__ okT, float* __restrict__ ov)
{
    __shared__ float As[GBK][GBM + 4];   // A transposed [k][m]
    __shared__ float Bs[GBK][GBN + 4];
    int z = blockIdx.z;
    const float* X = (z == 0) ? Xq : (z == 1) ? Xk : Xv;
    const float* W = (z == 0) ? Wq : (z == 1) ? Wk : Wv;
    const float* bias = (z == 0) ? bq : (z == 1) ? bk : bv;
    float* out = (z == 0) ? oq : (z == 1) ? okT : ov;
    const float scale = (z == 0) ? 0.125f : 1.0f;

    int tid = threadIdx.x;
    int tx = tid & 15, ty = tid >> 4;
    int m0 = blockIdx.y * GBM;
    int n0 = blockIdx.x * GBN;
    float acc[8][4] = {};
    for (int k0 = 0; k0 < DD; k0 += GBK) {
#pragma unroll
        for (int rep = 0; rep < 2; rep++) {
            int i = tid + 256 * rep;       // 0..511 float4 slots of A-tile
            int m = i >> 2, kq = i & 3;
            float4 xv = *(const float4*)(X + (size_t)(m0 + m) * DD + k0 + 4 * kq);
            As[4 * kq + 0][m] = xv.x; As[4 * kq + 1][m] = xv.y;
            As[4 * kq + 2][m] = xv.z; As[4 * kq + 3][m] = xv.w;
        }
        {
            int r = tid >> 4, c = tid & 15;
            float4 wv = *(const float4*)(W + (size_t)(k0 + r) * DD + n0 + 4 * c);
            *(float4*)&Bs[r][4 * c] = wv;
        }
        __syncthreads();
#pragma unroll
        for (int kk = 0; kk < GBK; kk++) {
            float4 a0 = *(float4*)&As[kk][ty * 8];
            float4 a1 = *(float4*)&As[kk][ty * 8 + 4];
            float4 b0 = *(float4*)&Bs[kk][tx * 4];
            float a[8] = {a0.x, a0.y, a0.z, a0.w, a1.x, a1.y, a1.z, a1.w};
            float bb[4] = {b0.x, b0.y, b0.z, b0.w};
#pragma unroll
            for (int i = 0; i < 8; i++)
#pragma unroll
                for (int j = 0; j < 4; j++) acc[i][j] += a[i] * bb[j];
        }
        __syncthreads();
    }
#pragma unroll
    for (int i = 0; i < 8; i++) {
        int m = m0 + ty * 8 + i;
        int b = m >> 9, s = m & 511;
#pragma unroll
        for (int j = 0; j < 4; j++) {
            int n = n0 + tx * 4 + j;
            int h = n >> 6, d = n & 63;
            float val = (acc[i][j] + bias[n]) * scale;
            size_t idx;
            if (z == 1)
                idx = ((((size_t)b * HH + h) * DHH + d) * SS + s);
            else
                idx = ((((size_t)b * HH + h) * SS + s) * DHH + d);
            out[idx] = val;
        }
    }
}

// K3: output GEMM  out = ctx @ Wo + bo
__global__ __launch_bounds__(256) void gemm_out(
    const float* __restrict__ Xf, const float* __restrict__ W,
    const float* __restrict__ bias, float* __restrict__ out)
{
    __shared__ float As[GBK][GBM + 4];
    __shared__ float Bs[GBK][GBN + 4];
    int tid = threadIdx.x;
    int tx = tid & 15, ty = tid >> 4;
    int m0 = blockIdx.y * GBM;
    int n0 = blockIdx.x * GBN;
    float acc[8][4] = {};
    for (int k0 = 0; k0 < DD; k0 += GBK) {
#pragma unroll
        for (int rep = 0; rep < 2; rep++) {
            int i = tid + 256 * rep;
            int m = i >> 2, kq = i & 3;
            float4 xv = *(const float4*)(Xf + (size_t)(m0 + m) * DD + k0 + 4 * kq);
            As[4 * kq + 0][m] = xv.x; As[4 * kq + 1][m] = xv.y;
            As[4 * kq + 2][m] = xv.z; As[4 * kq + 3][m] = xv.w;
        }
        {
            int r = tid >> 4, c = tid & 15;
            float4 wv = *(const float4*)(W + (size_t)(k0 + r) * DD + n0 + 4 * c);
            *(float4*)&Bs[r][4 * c] = wv;
        }
        __syncthreads();
#pragma unroll
        for (int kk = 0; kk < GBK; kk++) {
            float4 a0 = *(float4*)&As[kk][ty * 8];
            float4 a1 = *(float4*)&As[kk][ty * 8 + 4];
            float4 b0 = *(float4*)&Bs[kk][tx * 4];
            float a[8] = {a0.x, a0.y, a0.z, a0.w, a1.x, a1.y, a1.z, a1.w};
            float bb[4] = {b0.x, b0.y, b0.z, b0.w};
#pragma unroll
            for (int i = 0; i < 8; i++)
#pragma unroll
                for (int j = 0; j < 4; j++) acc[i][j] += a[i] * bb[j];
        }
        __syncthreads();
    }
#pragma unroll
    for (int i = 0; i < 8; i++) {
        int m = m0 + ty * 8 + i;
#pragma unroll
        for (int j = 0; j < 4; j++) {
            int n = n0 + tx * 4 + j;
            out[(size_t)m * DD + n] = acc[i][j] + bias[n];
        }
    }
}

// ---------------------------------------------------------------------------
// K2 (fused attention) v3: as v2 but with coalesced structure load
// (flat float2 indexing: consecutive lanes -> consecutive 8B).
// ---------------------------------------------------------------------------
__global__ __launch_bounds__(256) void attn_fused(
    const float* __restrict__ q,    // (B,H,S,DH)
    const float* __restrict__ kT,   // (B,H,DH,S)
    const float* __restrict__ v,    // (B,H,S,DH)
    const float* __restrict__ structure, // (B,S,S,30) f32
    const int* __restrict__ mask,   // (B,S,S) int32 0/1
    const float* __restrict__ Wsk,  // (30,64)
    const float* __restrict__ bsk,  // (64)
    const float* __restrict__ Wsv,  // (30,64)
    const float* __restrict__ bsv,  // (64)
    float* __restrict__ ctx,        // (B,S,D)
    float* __restrict__ top_attn)   // (B,S,S) f32
{
    __shared__ float qs[HH][DHH];               //  3072 B
    __shared__ unsigned short stT[SDD][LP];     // 31200 B  structure row, transposed, bf16
    __shared__ float qt_s[HH][SDD];             //  1440 B
    __shared__ float qb_s[HH];                  //    48 B
    __shared__ float astr_s[HH][SDD];           //  1440 B
    __shared__ unsigned short at[HH][LP];       // 12480 B  attn weights bf16 [h][k]

    int tid = threadIdx.x;
    int lane = tid & 63, wave = tid >> 6;

    // XCD-aware swizzle: blocks on one XCD share one batch's kT/v slab (3 MB < 4 MB L2)
    int blk = blockIdx.x;
    int xcd = blk & 7;
    int b = xcd >> 1;
    int qp = ((xcd & 1) << 8) | (blk >> 3);

    // --- load q rows for all heads ---
    for (int i = tid; i < HH * DHH; i += 256) {
        int h = i >> 6, d = i & 63;
        qs[h][d] = q[(((size_t)b * HH + h) * SS + qp) * DHH + d];
    }
    // --- load structure row (b,qp,:,:) f32 -> transposed bf16 LDS, coalesced flat ---
    {
        const nfloat2* sp2 = (const nfloat2*)(structure + ((size_t)b * SS + qp) * (size_t)(SS * SDD));
        for (int i = tid; i < SS * SDD / 2; i += 256) {   // 7680 float2, consecutive lanes
            nfloat2 xv = __builtin_nontemporal_load(sp2 + i);
            int k = i / 15;           // magic-mul division
            int w = i - k * 15;
            stT[2 * w][k] = tobf(xv.x);
            stT[2 * w + 1][k] = tobf(xv.y);
        }
    }
    __syncthreads();

    // --- qt[h][si] = qs[h] . Wsk[si]; qb[h] = qs[h] . bsk ---
    for (int i = tid; i < HH * SDD; i += 256) {
        int h = i / SDD, si = i % SDD;
        const float4* wp = (const float4*)(Wsk + si * DHH);
        const float4* qp4 = (const float4*)qs[h];
        float a = 0.f;
#pragma unroll
        for (int d4 = 0; d4 < 16; d4++) {
            float4 wv = wp[d4];
            float4 qv = qp4[d4];
            a += qv.x * wv.x + qv.y * wv.y + qv.z * wv.z + qv.w * wv.w;
        }
        qt_s[h][si] = a;
    }
    if (tid < HH) {
        const float4* bp = (const float4*)bsk;
        const float4* qp4 = (const float4*)qs[tid];
        float a = 0.f;
#pragma unroll
        for (int d4 = 0; d4 < 16; d4++) {
            float4 wv = bp[d4];
            float4 qv = qp4[d4];
            a += qv.x * wv.x + qv.y * wv.y + qv.z * wv.z + qv.w * wv.w;
        }
        qb_s[tid] = a;
    }
    __syncthreads();

    // --- scores: wave w -> heads 3w..3w+2, lane owns k = 8*lane..8*lane+7 ---
    int h0 = wave * 3;
    float attnv[3][8];
#pragma unroll
    for (int h = 0; h < 3; h++)
#pragma unroll
        for (int j = 0; j < 8; j++) attnv[h][j] = 0.f;

    // structure-score term: b128 reads of stT, broadcast qt
#pragma unroll 2
    for (int si = 0; si < SDD; si++) {
        uint4 sv4 = *(const uint4*)&stT[si][8 * lane];
        float t[8];
        unp8(sv4, t);
#pragma unroll
        for (int h = 0; h < 3; h++) {
            float qt = qt_s[h0 + h][si];
#pragma unroll
            for (int j = 0; j < 8; j++) attnv[h][j] += qt * t[j];
        }
    }

    // q.k term: float4 kT loads, fully coalesced
    {
        const float* kbase = kT + (((size_t)b * HH + h0) * DHH) * SS + 8 * lane;
#pragma unroll
        for (int h = 0; h < 3; h++) {
            const float* kp = kbase + (size_t)h * (DHH * SS);
            const float4* qp4 = (const float4*)qs[h0 + h];
            float acc[8] = {0.f, 0.f, 0.f, 0.f, 0.f, 0.f, 0.f, 0.f};
#pragma unroll 4
            for (int d4 = 0; d4 < 16; d4++) {
                float4 qv = qp4[d4];
                const float* kd = kp + (size_t)(4 * d4) * SS;
#pragma unroll
                for (int dd = 0; dd < 4; dd++) {
                    float qd = ((const float*)&qv)[dd];
                    float4 ka = *(const float4*)(kd + (size_t)dd * SS);
                    float4 kb = *(const float4*)(kd + (size_t)dd * SS + 4);
                    acc[0] += qd * ka.x; acc[1] += qd * ka.y;
                    acc[2] += qd * ka.z; acc[3] += qd * ka.w;
                    acc[4] += qd * kb.x; acc[5] += qd * kb.y;
                    acc[6] += qd * kb.z; acc[7] += qd * kb.w;
                }
            }
            float qb = qb_s[h0 + h];
#pragma unroll
            for (int j = 0; j < 8; j++) attnv[h][j] += acc[j] + qb;
        }
    }

    // mask
    {
        const int* mrow = mask + ((size_t)b * SS + qp) * SS + 8 * lane;
        nint4 m0v = __builtin_nontemporal_load((const nint4*)mrow);
        nint4 m1v = __builtin_nontemporal_load(((const nint4*)mrow) + 1);
        int mm[8] = {m0v.x, m0v.y, m0v.z, m0v.w, m1v.x, m1v.y, m1v.z, m1v.w};
#pragma unroll
        for (int h = 0; h < 3; h++)
#pragma unroll
            for (int j = 0; j < 8; j++)
                if (mm[j]) attnv[h][j] = -1e18f;
    }

    // --- softmax per head, in-wave ---
#pragma unroll
    for (int h = 0; h < 3; h++) {
        float m = attnv[h][0];
#pragma unroll
        for (int j = 1; j < 8; j++) m = fmaxf(m, attnv[h][j]);
#pragma unroll
        for (int off = 32; off > 0; off >>= 1) m = fmaxf(m, __shfl_xor(m, off));
        float l = 0.f;
#pragma unroll
        for (int j = 0; j < 8; j++) { attnv[h][j] = __expf(attnv[h][j] - m); l += attnv[h][j]; }
#pragma unroll
        for (int off = 32; off > 0; off >>= 1) l += __shfl_xor(l, off);
        float inv = 1.f / l;
        float a[8];
#pragma unroll
        for (int j = 0; j < 8; j++) a[j] = attnv[h][j] * inv;
        uint4 pk;
        pk.x = (uint32_ty)tobf(a[0]) | ((uint32_ty)tobf(a[1]) << 16);
        pk.y = (uint32_ty)tobf(a[2]) | ((uint32_ty)tobf(a[3]) << 16);
        pk.z = (uint32_ty)tobf(a[4]) | ((uint32_ty)tobf(a[5]) << 16);
        pk.w = (uint32_ty)tobf(a[6]) | ((uint32_ty)tobf(a[7]) << 16);
        *(uint4*)&at[h0 + h][8 * lane] = pk;
        if (h0 + h == 0) {
            float* tp = top_attn + ((size_t)b * SS + qp) * SS + 8 * lane;
            nfloat4 w0 = {a[0], a[1], a[2], a[3]};
            nfloat4 w1 = {a[4], a[5], a[6], a[7]};
            __builtin_nontemporal_store(w0, (nfloat4*)tp);
            __builtin_nontemporal_store(w1, ((nfloat4*)tp) + 1);
        }
    }
    __syncthreads();

    // --- astr[h][si] = sum_k attn[h][k] * structure[k][si] : all-b128 LDS ---
    if (tid < 180) {
        int h = tid / 15, sp = tid % 15;
        int si0 = 2 * sp, si1 = si0 + 1;
        float a0e = 0.f, a0o = 0.f, a1e = 0.f, a1o = 0.f;
#pragma unroll 2
        for (int j = 0; j < 64; j++) {
            uint4 av = *(const uint4*)&at[h][8 * j];
            uint4 s0 = *(const uint4*)&stT[si0][8 * j];
            uint4 s1 = *(const uint4*)&stT[si1][8 * j];
            float a[8], t0[8], t1[8];
            unp8(av, a); unp8(s0, t0); unp8(s1, t1);
#pragma unroll
            for (int t = 0; t < 8; t += 2) {
                a0e += a[t] * t0[t];     a0o += a[t + 1] * t0[t + 1];
                a1e += a[t] * t1[t];     a1o += a[t + 1] * t1[t + 1];
            }
        }
        astr_s[h][si0] = a0e + a0o;
        astr_s[h][si1] = a1e + a1o;
    }
    __syncthreads();

    // --- ctx: thread=(h, dq) computes 4 floats; attn@v (float4 loads) + astr@Wsv + bsv ---
    if (tid < 192) {
        int h = tid >> 4, dq = tid & 15;
        const float* vp = v + ((size_t)b * HH + h) * (size_t)(SS * DHH) + 4 * dq;
        float4 ae; ae.x = ae.y = ae.z = ae.w = 0.f;
        float4 ao; ao.x = ao.y = ao.z = ao.w = 0.f;
#pragma unroll 2
        for (int j = 0; j < 64; j++) {
            uint4 av = *(const uint4*)&at[h][8 * j];
            float a[8];
            unp8(av, a);
            const float* vk = vp + (size_t)(8 * j) * DHH;
#pragma unroll
            for (int t = 0; t < 8; t += 2) {
                float4 v0 = *(const float4*)(vk + (size_t)t * DHH);
                float4 v1 = *(const float4*)(vk + (size_t)(t + 1) * DHH);
                ae.x += a[t] * v0.x; ae.y += a[t] * v0.y;
                ae.z += a[t] * v0.z; ae.w += a[t] * v0.w;
                ao.x += a[t + 1] * v1.x; ao.y += a[t + 1] * v1.y;
                ao.z += a[t + 1] * v1.z; ao.w += a[t + 1] * v1.w;
            }
        }
        float4 sa = *(const float4*)(bsv + 4 * dq);
#pragma unroll
        for (int si = 0; si < SDD; si++) {
            float as = astr_s[h][si];
            float4 wv = *(const float4*)(Wsv + si * DHH + 4 * dq);
            sa.x += as * wv.x; sa.y += as * wv.y;
            sa.z += as * wv.z; sa.w += as * wv.w;
        }
        float4 outv;
        outv.x = ae.x + ao.x + sa.x;
        outv.y = ae.y + ao.y + sa.y;
        outv.z = ae.z + ao.z + sa.z;
        outv.w = ae.w + ao.w + sa.w;
        *(float4*)(ctx + ((size_t)b * SS + qp) * DD + h * DHH + 4 * dq) = outv;
    }
}

// ---------------------------------------------------------------------------
extern "C" void kernel_launch(void* const* d_in, const int* in_sizes, int n_in,
                              void* d_out, int out_size, void* d_ws, size_t ws_size,
                              hipStream_t stream)
{
    const float* key       = (const float*)d_in[0];
    const float* value     = (const float*)d_in[1];
    const float* query     = (const float*)d_in[2];
    const float* structure = (const float*)d_in[3];
    const int*   mask      = (const int*)d_in[4];
    const float* Wq  = (const float*)d_in[5];
    const float* bq  = (const float*)d_in[6];
    const float* Wk  = (const float*)d_in[7];
    const float* bk  = (const float*)d_in[8];
    const float* Wv  = (const float*)d_in[9];
    const float* bv  = (const float*)d_in[10];
    const float* Wsk = (const float*)d_in[11];
    const float* bsk = (const float*)d_in[12];
    const float* Wsv = (const float*)d_in[13];
    const float* bsv = (const float*)d_in[14];
    const float* Wo  = (const float*)d_in[15];
    const float* bo  = (const float*)d_in[16];

    float* out_main = (float*)d_out;                         // (B,S,D)
    float* out_attn = (float*)d_out + (size_t)BB * SS * DD;  // (B,S,S)

    float* ws = (float*)d_ws;
    float* q_buf   = ws;                  // (B,H,S,DH)  1,572,864
    float* kT_buf  = ws + 1572864;        // (B,H,DH,S)  1,572,864
    float* v_buf   = ws + 3145728;        // (B,H,S,DH)  1,572,864
    float* ctx_buf = ws + 4718592;        // (B,S,D)     1,572,864

    dim3 gblk(256);
    dim3 ggrd3(DD / GBN, (BB * SS) / GBM, 3);   // 12 x 16 x 3
    dim3 ggrd(DD / GBN, (BB * SS) / GBM);       // 12 x 16

    gemm_proj3<<<ggrd3, gblk, 0, stream>>>(query, key, value, Wq, Wk, Wv,
                                           bq, bk, bv, q_buf, kT_buf, v_buf);

    attn_fused<<<BB * SS, 256, 0, stream>>>(q_buf, kT_buf, v_buf, structure, mask,
                                            Wsk, bsk, Wsv, bsv, ctx_buf, out_attn);

    gemm_out<<<ggrd, gblk, 0, stream>>>(ctx_buf, Wo, bo, out_main);
}

// Round 5
// 607.016 us; speedup vs baseline: 1.1127x; 1.1127x over previous
//
#include <hip/hip_runtime.h>
#include <hip/hip_bf16.h>

typedef unsigned int uint32_ty;

// native vector types for nontemporal builtins (HIP_vector_type not accepted)
typedef float  nfloat2 __attribute__((ext_vector_type(2)));
typedef float  nfloat4 __attribute__((ext_vector_type(4)));
typedef int    nint4   __attribute__((ext_vector_type(4)));

// Problem constants
#define BB 4
#define SS 512
#define DD 768
#define HH 12
#define DHH 64
#define SDD 30

// padded LDS row stride (elements) for bf16 rows of length 512
#define LP 520

__device__ __forceinline__ float bfu(unsigned short u) {
    return __uint_as_float(((uint32_ty)u) << 16);
}
__device__ __forceinline__ unsigned short tobf(float f) {
    return __bfloat16_as_ushort(__float2bfloat16(f));
}
__device__ __forceinline__ void unp8(uint4 u, float* t) {
    t[0] = __uint_as_float(u.x << 16);
    t[1] = __uint_as_float(u.x & 0xFFFF0000u);
    t[2] = __uint_as_float(u.y << 16);
    t[3] = __uint_as_float(u.y & 0xFFFF0000u);
    t[4] = __uint_as_float(u.z << 16);
    t[5] = __uint_as_float(u.z & 0xFFFF0000u);
    t[6] = __uint_as_float(u.w << 16);
    t[7] = __uint_as_float(u.w & 0xFFFF0000u);
}
__device__ __forceinline__ void unp4(uint2 u, float* t) {
    t[0] = __uint_as_float(u.x << 16);
    t[1] = __uint_as_float(u.x & 0xFFFF0000u);
    t[2] = __uint_as_float(u.y << 16);
    t[3] = __uint_as_float(u.y & 0xFFFF0000u);
}

// ---------------------------------------------------------------------------
// K1: fused projection GEMMs (R2-proven 64x64x32 tiling, 4x4 microtile).
// z=0 -> q f32 (B,H,S,DH) scaled 1/8; z=1 -> kT bf16 (B,H,DH,S);
// z=2 -> v bf16 (B,H,S,DH).
// ---------------------------------------------------------------------------
#define TM 64
#define TN 64
#define TKK 32

__global__ __launch_bounds__(256) void gemm_proj3(
    const float* __restrict__ Xq, const float* __restrict__ Xk, const float* __restrict__ Xv,
    const float* __restrict__ Wq, const float* __restrict__ Wk, const float* __restrict__ Wv,
    const float* __restrict__ bq, const float* __restrict__ bk, const float* __restrict__ bv,
    float* __restrict__ oq, unsigned short* __restrict__ okT, unsigned short* __restrict__ ov)
{
    __shared__ float As[TKK][TM + 4];
    __shared__ float Bs[TKK][TN + 4];
    int z = blockIdx.z;
    const float* X = (z == 0) ? Xq : (z == 1) ? Xk : Xv;
    const float* W = (z == 0) ? Wq : (z == 1) ? Wk : Wv;
    const float* bias = (z == 0) ? bq : (z == 1) ? bk : bv;
    const float scale = (z == 0) ? 0.125f : 1.0f;

    int tx = threadIdx.x, ty = threadIdx.y;
    int tid = ty * 16 + tx;
    int m0 = blockIdx.y * TM;
    int n0 = blockIdx.x * TN;
    float acc[4][4] = {};
    for (int k0 = 0; k0 < DD; k0 += TKK) {
#pragma unroll
        for (int rep = 0; rep < 2; rep++) {
            int f = tid + 256 * rep;
            int r = f >> 3;
            int c = f & 7;
            float4 xv = *(const float4*)(X + (size_t)(m0 + r) * DD + k0 + 4 * c);
            As[4 * c + 0][r] = xv.x; As[4 * c + 1][r] = xv.y;
            As[4 * c + 2][r] = xv.z; As[4 * c + 3][r] = xv.w;
        }
#pragma unroll
        for (int rep = 0; rep < 2; rep++) {
            int f = tid + 256 * rep;
            int r = f >> 4;
            int c = f & 15;
            float4 wv = *(const float4*)(W + (size_t)(k0 + r) * DD + n0 + 4 * c);
            *(float4*)&Bs[r][4 * c] = wv;
        }
        __syncthreads();
#pragma unroll 8
        for (int kk = 0; kk < TKK; kk++) {
            float4 av = *(float4*)&As[kk][ty * 4];
            float4 bv4 = *(float4*)&Bs[kk][tx * 4];
            float a[4] = {av.x, av.y, av.z, av.w};
            float bb[4] = {bv4.x, bv4.y, bv4.z, bv4.w};
#pragma unroll
            for (int i = 0; i < 4; i++)
#pragma unroll
                for (int j = 0; j < 4; j++) acc[i][j] += a[i] * bb[j];
        }
        __syncthreads();
    }
#pragma unroll
    for (int i = 0; i < 4; i++) {
        int m = m0 + ty * 4 + i;
        int b = m >> 9, s = m & 511;
#pragma unroll
        for (int j = 0; j < 4; j++) {
            int n = n0 + tx * 4 + j;
            int h = n >> 6, d = n & 63;
            float val = (acc[i][j] + bias[n]) * scale;
            if (z == 0) {
                oq[((((size_t)b * HH + h) * SS + s) * DHH + d)] = val;
            } else if (z == 1) {
                okT[((((size_t)b * HH + h) * DHH + d) * SS + s)] = tobf(val);
            } else {
                ov[((((size_t)b * HH + h) * SS + s) * DHH + d)] = tobf(val);
            }
        }
    }
}

// ---------------------------------------------------------------------------
// K3: output GEMM  out = ctx @ Wo + bo  (R2-proven code, unchanged)
// ---------------------------------------------------------------------------
__global__ __launch_bounds__(256) void gemm_out(
    const float* __restrict__ Xf, const float* __restrict__ W,
    const float* __restrict__ bias, float* __restrict__ out)
{
    __shared__ float As[TKK][TM + 4];
    __shared__ float Bs[TKK][TN + 4];
    int tx = threadIdx.x, ty = threadIdx.y;
    int tid = ty * 16 + tx;
    int m0 = blockIdx.y * TM;
    int n0 = blockIdx.x * TN;
    float acc[4][4] = {};
    for (int k0 = 0; k0 < DD; k0 += TKK) {
#pragma unroll
        for (int rep = 0; rep < 2; rep++) {
            int f = tid + 256 * rep;
            int r = f >> 3, c = f & 7;
            float4 xv = *(const float4*)(Xf + (size_t)(m0 + r) * DD + k0 + 4 * c);
            As[4 * c + 0][r] = xv.x; As[4 * c + 1][r] = xv.y;
            As[4 * c + 2][r] = xv.z; As[4 * c + 3][r] = xv.w;
        }
#pragma unroll
        for (int rep = 0; rep < 2; rep++) {
            int f = tid + 256 * rep;
            int r = f >> 4, c = f & 15;
            float4 wv = *(const float4*)(W + (size_t)(k0 + r) * DD + n0 + 4 * c);
            *(float4*)&Bs[r][4 * c] = wv;
        }
        __syncthreads();
#pragma unroll 8
        for (int kk = 0; kk < TKK; kk++) {
            float4 av = *(float4*)&As[kk][ty * 4];
            float4 bv4 = *(float4*)&Bs[kk][tx * 4];
            float a[4] = {av.x, av.y, av.z, av.w};
            float bb[4] = {bv4.x, bv4.y, bv4.z, bv4.w};
#pragma unroll
            for (int i = 0; i < 4; i++)
#pragma unroll
                for (int j = 0; j < 4; j++) acc[i][j] += a[i] * bb[j];
        }
        __syncthreads();
    }
#pragma unroll
    for (int i = 0; i < 4; i++) {
        int m = m0 + ty * 4 + i;
#pragma unroll
        for (int j = 0; j < 4; j++) {
            int n = n0 + tx * 4 + j;
            out[(size_t)m * DD + n] = acc[i][j] + bias[n];
        }
    }
}

// ---------------------------------------------------------------------------
// K2 (fused attention) v4: bf16 kT/v (halved L2 traffic & VMEM instrs),
// R2 structure-load pattern (faster than flat), XCD-aware block swizzle.
// ---------------------------------------------------------------------------
__global__ __launch_bounds__(256) void attn_fused(
    const float* __restrict__ q,          // (B,H,S,DH) f32
    const unsigned short* __restrict__ kT,// (B,H,DH,S) bf16
    const unsigned short* __restrict__ v, // (B,H,S,DH) bf16
    const float* __restrict__ structure,  // (B,S,S,30) f32
    const int* __restrict__ mask,         // (B,S,S) int32 0/1
    const float* __restrict__ Wsk,  // (30,64)
    const float* __restrict__ bsk,  // (64)
    const float* __restrict__ Wsv,  // (30,64)
    const float* __restrict__ bsv,  // (64)
    float* __restrict__ ctx,        // (B,S,D)
    float* __restrict__ top_attn)   // (B,S,S) f32
{
    __shared__ float qs[HH][DHH];               //  3072 B
    __shared__ unsigned short stT[SDD][LP];     // 31200 B  structure row, transposed, bf16
    __shared__ float qt_s[HH][SDD];             //  1440 B
    __shared__ float qb_s[HH];                  //    48 B
    __shared__ float astr_s[HH][SDD];           //  1440 B
    __shared__ unsigned short at[HH][LP];       // 12480 B  attn weights bf16 [h][k]

    int tid = threadIdx.x;
    int lane = tid & 63, wave = tid >> 6;

    // XCD-aware swizzle: blocks on one XCD share one batch's kT/v slab (1.5 MB < 4 MB L2)
    int blk = blockIdx.x;
    int xcd = blk & 7;
    int b = xcd >> 1;
    int qp = ((xcd & 1) << 8) | (blk >> 3);

    // --- load q rows for all heads ---
    for (int i = tid; i < HH * DHH; i += 256) {
        int h = i >> 6, d = i & 63;
        qs[h][d] = q[(((size_t)b * HH + h) * SS + qp) * DHH + d];
    }
    // --- load structure row (b,qp,:,:) f32 -> transposed bf16 LDS (R2 pattern) ---
    {
        const float* srow = structure + ((size_t)b * SS + qp) * (size_t)(SS * SDD);
        for (int k = tid; k < SS; k += 256) {
            const nfloat2* rp = (const nfloat2*)(srow + (size_t)k * SDD);
#pragma unroll
            for (int w = 0; w < 15; w++) {
                nfloat2 xv = __builtin_nontemporal_load(rp + w);
                stT[2 * w][k] = tobf(xv.x);
                stT[2 * w + 1][k] = tobf(xv.y);
            }
        }
    }
    __syncthreads();

    // --- qt[h][si] = qs[h] . Wsk[si]; qb[h] = qs[h] . bsk ---
    for (int i = tid; i < HH * SDD; i += 256) {
        int h = i / SDD, si = i % SDD;
        const float4* wp = (const float4*)(Wsk + si * DHH);
        const float4* qp4 = (const float4*)qs[h];
        float a = 0.f;
#pragma unroll
        for (int d4 = 0; d4 < 16; d4++) {
            float4 wv = wp[d4];
            float4 qv = qp4[d4];
            a += qv.x * wv.x + qv.y * wv.y + qv.z * wv.z + qv.w * wv.w;
        }
        qt_s[h][si] = a;
    }
    if (tid < HH) {
        const float4* bp = (const float4*)bsk;
        const float4* qp4 = (const float4*)qs[tid];
        float a = 0.f;
#pragma unroll
        for (int d4 = 0; d4 < 16; d4++) {
            float4 wv = bp[d4];
            float4 qv = qp4[d4];
            a += qv.x * wv.x + qv.y * wv.y + qv.z * wv.z + qv.w * wv.w;
        }
        qb_s[tid] = a;
    }
    __syncthreads();

    // --- scores: wave w -> heads 3w..3w+2, lane owns k = 8*lane..8*lane+7 ---
    int h0 = wave * 3;
    float attnv[3][8];
#pragma unroll
    for (int h = 0; h < 3; h++)
#pragma unroll
        for (int j = 0; j < 8; j++) attnv[h][j] = 0.f;

    // structure-score term: b128 reads of stT, broadcast qt
#pragma unroll 2
    for (int si = 0; si < SDD; si++) {
        uint4 sv4 = *(const uint4*)&stT[si][8 * lane];
        float t[8];
        unp8(sv4, t);
#pragma unroll
        for (int h = 0; h < 3; h++) {
            float qt = qt_s[h0 + h][si];
#pragma unroll
            for (int j = 0; j < 8; j++) attnv[h][j] += qt * t[j];
        }
    }

    // q.k term: bf16 kT, one uint4 = 8 k-values per d-row; fully coalesced
    {
        const unsigned short* kbase = kT + (((size_t)b * HH + h0) * DHH) * SS + 8 * lane;
#pragma unroll
        for (int h = 0; h < 3; h++) {
            const unsigned short* kp = kbase + (size_t)h * (DHH * SS);
            float acc[8] = {0.f, 0.f, 0.f, 0.f, 0.f, 0.f, 0.f, 0.f};
#pragma unroll 8
            for (int d = 0; d < DHH; d++) {
                float qd = qs[h0 + h][d];
                uint4 kv = *(const uint4*)(kp + (size_t)d * SS);
                float t[8];
                unp8(kv, t);
#pragma unroll
                for (int j = 0; j < 8; j++) acc[j] += qd * t[j];
            }
            float qb = qb_s[h0 + h];
#pragma unroll
            for (int j = 0; j < 8; j++) attnv[h][j] += acc[j] + qb;
        }
    }

    // mask
    {
        const int* mrow = mask + ((size_t)b * SS + qp) * SS + 8 * lane;
        nint4 m0v = __builtin_nontemporal_load((const nint4*)mrow);
        nint4 m1v = __builtin_nontemporal_load(((const nint4*)mrow) + 1);
        int mm[8] = {m0v.x, m0v.y, m0v.z, m0v.w, m1v.x, m1v.y, m1v.z, m1v.w};
#pragma unroll
        for (int h = 0; h < 3; h++)
#pragma unroll
            for (int j = 0; j < 8; j++)
                if (mm[j]) attnv[h][j] = -1e18f;
    }

    // --- softmax per head, in-wave ---
#pragma unroll
    for (int h = 0; h < 3; h++) {
        float m = attnv[h][0];
#pragma unroll
        for (int j = 1; j < 8; j++) m = fmaxf(m, attnv[h][j]);
#pragma unroll
        for (int off = 32; off > 0; off >>= 1) m = fmaxf(m, __shfl_xor(m, off));
        float l = 0.f;
#pragma unroll
        for (int j = 0; j < 8; j++) { attnv[h][j] = __expf(attnv[h][j] - m); l += attnv[h][j]; }
#pragma unroll
        for (int off = 32; off > 0; off >>= 1) l += __shfl_xor(l, off);
        float inv = 1.f / l;
        float a[8];
#pragma unroll
        for (int j = 0; j < 8; j++) a[j] = attnv[h][j] * inv;
        uint4 pk;
        pk.x = (uint32_ty)tobf(a[0]) | ((uint32_ty)tobf(a[1]) << 16);
        pk.y = (uint32_ty)tobf(a[2]) | ((uint32_ty)tobf(a[3]) << 16);
        pk.z = (uint32_ty)tobf(a[4]) | ((uint32_ty)tobf(a[5]) << 16);
        pk.w = (uint32_ty)tobf(a[6]) | ((uint32_ty)tobf(a[7]) << 16);
        *(uint4*)&at[h0 + h][8 * lane] = pk;
        if (h0 + h == 0) {
            float* tp = top_attn + ((size_t)b * SS + qp) * SS + 8 * lane;
            nfloat4 w0 = {a[0], a[1], a[2], a[3]};
            nfloat4 w1 = {a[4], a[5], a[6], a[7]};
            __builtin_nontemporal_store(w0, (nfloat4*)tp);
            __builtin_nontemporal_store(w1, ((nfloat4*)tp) + 1);
        }
    }
    __syncthreads();

    // --- astr[h][si] = sum_k attn[h][k] * structure[k][si] : all-b128 LDS ---
    if (tid < 180) {
        int h = tid / 15, sp = tid % 15;
        int si0 = 2 * sp, si1 = si0 + 1;
        float a0e = 0.f, a0o = 0.f, a1e = 0.f, a1o = 0.f;
#pragma unroll 2
        for (int j = 0; j < 64; j++) {
            uint4 av = *(const uint4*)&at[h][8 * j];
            uint4 s0 = *(const uint4*)&stT[si0][8 * j];
            uint4 s1 = *(const uint4*)&stT[si1][8 * j];
            float a[8], t0[8], t1[8];
            unp8(av, a); unp8(s0, t0); unp8(s1, t1);
#pragma unroll
            for (int t = 0; t < 8; t += 2) {
                a0e += a[t] * t0[t];     a0o += a[t + 1] * t0[t + 1];
                a1e += a[t] * t1[t];     a1o += a[t + 1] * t1[t + 1];
            }
        }
        astr_s[h][si0] = a0e + a0o;
        astr_s[h][si1] = a1e + a1o;
    }
    __syncthreads();

    // --- ctx: thread=(h, dq) computes 4 floats; attn@v (bf16 uint2 loads) + astr@Wsv + bsv ---
    if (tid < 192) {
        int h = tid >> 4, dq = tid & 15;
        const unsigned short* vp = v + ((size_t)b * HH + h) * (size_t)(SS * DHH) + 4 * dq;
        float4 ae; ae.x = ae.y = ae.z = ae.w = 0.f;
        float4 ao; ao.x = ao.y = ao.z = ao.w = 0.f;
#pragma unroll 2
        for (int j = 0; j < 64; j++) {
            uint4 av = *(const uint4*)&at[h][8 * j];
            float a[8];
            unp8(av, a);
            const unsigned short* vk = vp + (size_t)(8 * j) * DHH;
#pragma unroll
            for (int t = 0; t < 8; t += 2) {
                uint2 v0 = *(const uint2*)(vk + (size_t)t * DHH);
                uint2 v1 = *(const uint2*)(vk + (size_t)(t + 1) * DHH);
                float f0[4], f1[4];
                unp4(v0, f0); unp4(v1, f1);
                ae.x += a[t] * f0[0]; ae.y += a[t] * f0[1];
                ae.z += a[t] * f0[2]; ae.w += a[t] * f0[3];
                ao.x += a[t + 1] * f1[0]; ao.y += a[t + 1] * f1[1];
                ao.z += a[t + 1] * f1[2]; ao.w += a[t + 1] * f1[3];
            }
        }
        float4 sa = *(const float4*)(bsv + 4 * dq);
#pragma unroll
        for (int si = 0; si < SDD; si++) {
            float as = astr_s[h][si];
            float4 wv = *(const float4*)(Wsv + si * DHH + 4 * dq);
            sa.x += as * wv.x; sa.y += as * wv.y;
            sa.z += as * wv.z; sa.w += as * wv.w;
        }
        float4 outv;
        outv.x = ae.x + ao.x + sa.x;
        outv.y = ae.y + ao.y + sa.y;
        outv.z = ae.z + ao.z + sa.z;
        outv.w = ae.w + ao.w + sa.w;
        *(float4*)(ctx + ((size_t)b * SS + qp) * DD + h * DHH + 4 * dq) = outv;
    }
}

// ---------------------------------------------------------------------------
extern "C" void kernel_launch(void* const* d_in, const int* in_sizes, int n_in,
                              void* d_out, int out_size, void* d_ws, size_t ws_size,
                              hipStream_t stream)
{
    const float* key       = (const float*)d_in[0];
    const float* value     = (const float*)d_in[1];
    const float* query     = (const float*)d_in[2];
    const float* structure = (const float*)d_in[3];
    const int*   mask      = (const int*)d_in[4];
    const float* Wq  = (const float*)d_in[5];
    const float* bq  = (const float*)d_in[6];
    const float* Wk  = (const float*)d_in[7];
    const float* bk  = (const float*)d_in[8];
    const float* Wv  = (const float*)d_in[9];
    const float* bv  = (const float*)d_in[10];
    const float* Wsk = (const float*)d_in[11];
    const float* bsk = (const float*)d_in[12];
    const float* Wsv = (const float*)d_in[13];
    const float* bsv = (const float*)d_in[14];
    const float* Wo  = (const float*)d_in[15];
    const float* bo  = (const float*)d_in[16];

    float* out_main = (float*)d_out;                         // (B,S,D)
    float* out_attn = (float*)d_out + (size_t)BB * SS * DD;  // (B,S,S)

    float* ws = (float*)d_ws;
    float*          q_buf   = ws;                                  // (B,H,S,DH) f32: 1,572,864 floats
    unsigned short* kT_buf  = (unsigned short*)(ws + 1572864);     // (B,H,DH,S) bf16: 1,572,864 u16
    unsigned short* v_buf   = (unsigned short*)(ws + 2359296);     // (B,H,S,DH) bf16: 1,572,864 u16
    float*          ctx_buf = ws + 3145728;                        // (B,S,D) f32

    dim3 gblk(16, 16);
    dim3 ggrd3(DD / TN, (BB * SS) / TM, 3);   // 12 x 32 x 3
    dim3 ggrd(DD / TN, (BB * SS) / TM);       // 12 x 32

    gemm_proj3<<<ggrd3, gblk, 0, stream>>>(query, key, value, Wq, Wk, Wv,
                                           bq, bk, bv, q_buf, kT_buf, v_buf);

    attn_fused<<<BB * SS, 256, 0, stream>>>(q_buf, kT_buf, v_buf, structure, mask,
                                            Wsk, bsk, Wsv, bsv, ctx_buf, out_attn);

    gemm_out<<<ggrd, gblk, 0, stream>>>(ctx_buf, Wo, bo, out_main);
}

// Round 6
// 521.428 us; speedup vs baseline: 1.2953x; 1.1641x over previous
//
#include <hip/hip_runtime.h>
#include <hip/hip_bf16.h>

typedef unsigned int uint32_ty;

// native vector types (HIP_vector_type not accepted by some builtins)
typedef float  nfloat2 __attribute__((ext_vector_type(2)));
typedef float  nfloat4 __attribute__((ext_vector_type(4)));
typedef int    nint4   __attribute__((ext_vector_type(4)));
typedef short  bf16x8  __attribute__((ext_vector_type(8)));   // 8 bf16 (4 VGPRs)
typedef float  f32x4   __attribute__((ext_vector_type(4)));   // MFMA acc
typedef unsigned short ushort4n __attribute__((ext_vector_type(4)));

// Problem constants
#define BB 4
#define SS 512
#define DD 768
#define HH 12
#define DHH 64
#define SDD 30

// padded LDS row stride (elements) for bf16 rows of length 512
#define LP 520

__device__ __forceinline__ float bfu(unsigned short u) {
    return __uint_as_float(((uint32_ty)u) << 16);
}
__device__ __forceinline__ unsigned short tobf(float f) {
    return __bfloat16_as_ushort(__float2bfloat16(f));
}
__device__ __forceinline__ void unp8(uint4 u, float* t) {
    t[0] = __uint_as_float(u.x << 16);
    t[1] = __uint_as_float(u.x & 0xFFFF0000u);
    t[2] = __uint_as_float(u.y << 16);
    t[3] = __uint_as_float(u.y & 0xFFFF0000u);
    t[4] = __uint_as_float(u.z << 16);
    t[5] = __uint_as_float(u.z & 0xFFFF0000u);
    t[6] = __uint_as_float(u.w << 16);
    t[7] = __uint_as_float(u.w & 0xFFFF0000u);
}
__device__ __forceinline__ void unp4(uint2 u, float* t) {
    t[0] = __uint_as_float(u.x << 16);
    t[1] = __uint_as_float(u.x & 0xFFFF0000u);
    t[2] = __uint_as_float(u.y << 16);
    t[3] = __uint_as_float(u.y & 0xFFFF0000u);
}

// ---------------------------------------------------------------------------
// K1: fused projection GEMMs, MFMA bf16 (f32 accumulate).
// Tile 64x64, BK=64. 4 waves, each a 32x32 quadrant (2x2 of 16x16 frags).
// A staged [m][k] bf16; B staged transposed [n][k] bf16; k-stride padded to 72.
// z=0 -> q f32 (B,H,S,DH) scaled 1/8; z=1 -> kT bf16 (B,H,DH,S);
// z=2 -> v bf16 (B,H,S,DH).
// ---------------------------------------------------------------------------
#define MBM 64
#define MBN 64
#define MBK 64
#define LDK 72

__global__ __launch_bounds__(256) void gemm_proj3(
    const float* __restrict__ Xq, const float* __restrict__ Xk, const float* __restrict__ Xv,
    const float* __restrict__ Wq, const float* __restrict__ Wk, const float* __restrict__ Wv,
    const float* __restrict__ bq, const float* __restrict__ bk, const float* __restrict__ bv,
    float* __restrict__ oq, unsigned short* __restrict__ okT, unsigned short* __restrict__ ov)
{
    __shared__ unsigned short As[MBM][LDK];   // [m][k] bf16, 9216 B
    __shared__ unsigned short Bs[MBN][LDK];   // [n][k] bf16, 9216 B
    int z = blockIdx.z;
    const float* X = (z == 0) ? Xq : (z == 1) ? Xk : Xv;
    const float* W = (z == 0) ? Wq : (z == 1) ? Wk : Wv;
    const float* bias = (z == 0) ? bq : (z == 1) ? bk : bv;

    int tid = threadIdx.x;
    int lane = tid & 63, wave = tid >> 6;
    int m0 = blockIdx.y * MBM, n0 = blockIdx.x * MBN;
    int wm = (wave >> 1) * 32, wn = (wave & 1) * 32;
    int fr = lane & 15, fq = lane >> 4;   // fragment row/col index, k-group

    f32x4 acc[2][2];
#pragma unroll
    for (int i = 0; i < 2; i++)
#pragma unroll
        for (int j = 0; j < 2; j++) acc[i][j] = (f32x4){0.f, 0.f, 0.f, 0.f};

    for (int k0 = 0; k0 < DD; k0 += MBK) {
        // stage A: 64 rows x 64 k, coalesced float4, packed bf16x4 LDS writes
#pragma unroll
        for (int rep = 0; rep < 4; rep++) {
            int i = tid + 256 * rep;
            int r = i >> 4, c4 = i & 15;
            float4 xv = *(const float4*)(X + (size_t)(m0 + r) * DD + k0 + 4 * c4);
            ushort4n pk = {tobf(xv.x), tobf(xv.y), tobf(xv.z), tobf(xv.w)};
            *(ushort4n*)&As[r][4 * c4] = pk;
        }
        // stage B transposed: read W[k][n] coalesced, write Bs[n][k]
#pragma unroll
        for (int rep = 0; rep < 4; rep++) {
            int i = tid + 256 * rep;
            int r = i >> 4, c4 = i & 15;
            float4 wv = *(const float4*)(W + (size_t)(k0 + r) * DD + n0 + 4 * c4);
            Bs[4 * c4 + 0][r] = tobf(wv.x);
            Bs[4 * c4 + 1][r] = tobf(wv.y);
            Bs[4 * c4 + 2][r] = tobf(wv.z);
            Bs[4 * c4 + 3][r] = tobf(wv.w);
        }
        __syncthreads();
#pragma unroll
        for (int ks = 0; ks < 2; ks++) {
            bf16x8 a0 = *(bf16x8*)&As[wm + fr][ks * 32 + fq * 8];
            bf16x8 a1 = *(bf16x8*)&As[wm + 16 + fr][ks * 32 + fq * 8];
            bf16x8 b0 = *(bf16x8*)&Bs[wn + fr][ks * 32 + fq * 8];
            bf16x8 b1 = *(bf16x8*)&Bs[wn + 16 + fr][ks * 32 + fq * 8];
            acc[0][0] = __builtin_amdgcn_mfma_f32_16x16x32_bf16(a0, b0, acc[0][0], 0, 0, 0);
            acc[0][1] = __builtin_amdgcn_mfma_f32_16x16x32_bf16(a0, b1, acc[0][1], 0, 0, 0);
            acc[1][0] = __builtin_amdgcn_mfma_f32_16x16x32_bf16(a1, b0, acc[1][0], 0, 0, 0);
            acc[1][1] = __builtin_amdgcn_mfma_f32_16x16x32_bf16(a1, b1, acc[1][1], 0, 0, 0);
        }
        __syncthreads();
    }

    // epilogue: C/D layout col=lane&15, row=(lane>>4)*4+r  (guide §3, m89-verified)
#pragma unroll
    for (int i = 0; i < 2; i++) {
#pragma unroll
        for (int j = 0; j < 2; j++) {
            int n = n0 + wn + 16 * j + fr;
            int h = n >> 6, d = n & 63;
            float bn = bias[n];
            int mbase = m0 + wm + 16 * i + fq * 4;
            int b = mbase >> 9, sbase = mbase & 511;
            if (z == 1) {
                ushort4n pk;
#pragma unroll
                for (int r = 0; r < 4; r++) pk[r] = tobf(acc[i][j][r] + bn);
                *(ushort4n*)(okT + ((((size_t)b * HH + h) * DHH + d) * SS + sbase)) = pk;
            } else if (z == 0) {
#pragma unroll
                for (int r = 0; r < 4; r++)
                    oq[((((size_t)b * HH + h) * SS + sbase + r) * DHH + d)] =
                        (acc[i][j][r] + bn) * 0.125f;
            } else {
#pragma unroll
                for (int r = 0; r < 4; r++)
                    ov[((((size_t)b * HH + h) * SS + sbase + r) * DHH + d)] =
                        tobf(acc[i][j][r] + bn);
            }
        }
    }
}

// ---------------------------------------------------------------------------
// K3: output GEMM  out = ctx @ Wo + bo  (f32, R2-proven, unchanged)
// ---------------------------------------------------------------------------
#define TM 64
#define TN 64
#define TKK 32

__global__ __launch_bounds__(256) void gemm_out(
    const float* __restrict__ Xf, const float* __restrict__ W,
    const float* __restrict__ bias, float* __restrict__ out)
{
    __shared__ float As[TKK][TM + 4];
    __shared__ float Bs[TKK][TN + 4];
    int tx = threadIdx.x, ty = threadIdx.y;
    int tid = ty * 16 + tx;
    int m0 = blockIdx.y * TM;
    int n0 = blockIdx.x * TN;
    float acc[4][4] = {};
    for (int k0 = 0; k0 < DD; k0 += TKK) {
#pragma unroll
        for (int rep = 0; rep < 2; rep++) {
            int f = tid + 256 * rep;
            int r = f >> 3, c = f & 7;
            float4 xv = *(const float4*)(Xf + (size_t)(m0 + r) * DD + k0 + 4 * c);
            As[4 * c + 0][r] = xv.x; As[4 * c + 1][r] = xv.y;
            As[4 * c + 2][r] = xv.z; As[4 * c + 3][r] = xv.w;
        }
#pragma unroll
        for (int rep = 0; rep < 2; rep++) {
            int f = tid + 256 * rep;
            int r = f >> 4, c = f & 15;
            float4 wv = *(const float4*)(W + (size_t)(k0 + r) * DD + n0 + 4 * c);
            *(float4*)&Bs[r][4 * c] = wv;
        }
        __syncthreads();
#pragma unroll 8
        for (int kk = 0; kk < TKK; kk++) {
            float4 av = *(float4*)&As[kk][ty * 4];
            float4 bv4 = *(float4*)&Bs[kk][tx * 4];
            float a[4] = {av.x, av.y, av.z, av.w};
            float bb[4] = {bv4.x, bv4.y, bv4.z, bv4.w};
#pragma unroll
            for (int i = 0; i < 4; i++)
#pragma unroll
                for (int j = 0; j < 4; j++) acc[i][j] += a[i] * bb[j];
        }
        __syncthreads();
    }
#pragma unroll
    for (int i = 0; i < 4; i++) {
        int m = m0 + ty * 4 + i;
#pragma unroll
        for (int j = 0; j < 4; j++) {
            int n = n0 + tx * 4 + j;
            out[(size_t)m * DD + n] = acc[i][j] + bias[n];
        }
    }
}

// ---------------------------------------------------------------------------
// K2 (fused attention) v4: bf16 kT/v, R2 structure-load, XCD swizzle.
// (unchanged from R5 — 252 µs, VALUBusy 47%)
// ---------------------------------------------------------------------------
__global__ __launch_bounds__(256) void attn_fused(
    const float* __restrict__ q,          // (B,H,S,DH) f32
    const unsigned short* __restrict__ kT,// (B,H,DH,S) bf16
    const unsigned short* __restrict__ v, // (B,H,S,DH) bf16
    const float* __restrict__ structure,  // (B,S,S,30) f32
    const int* __restrict__ mask,         // (B,S,S) int32 0/1
    const float* __restrict__ Wsk,  // (30,64)
    const float* __restrict__ bsk,  // (64)
    const float* __restrict__ Wsv,  // (30,64)
    const float* __restrict__ bsv,  // (64)
    float* __restrict__ ctx,        // (B,S,D)
    float* __restrict__ top_attn)   // (B,S,S) f32
{
    __shared__ float qs[HH][DHH];               //  3072 B
    __shared__ unsigned short stT[SDD][LP];     // 31200 B  structure row, transposed, bf16
    __shared__ float qt_s[HH][SDD];             //  1440 B
    __shared__ float qb_s[HH];                  //    48 B
    __shared__ float astr_s[HH][SDD];           //  1440 B
    __shared__ unsigned short at[HH][LP];       // 12480 B  attn weights bf16 [h][k]

    int tid = threadIdx.x;
    int lane = tid & 63, wave = tid >> 6;

    // XCD-aware swizzle: blocks on one XCD share one batch's kT/v slab (1.5 MB < 4 MB L2)
    int blk = blockIdx.x;
    int xcd = blk & 7;
    int b = xcd >> 1;
    int qp = ((xcd & 1) << 8) | (blk >> 3);

    // --- load q rows for all heads ---
    for (int i = tid; i < HH * DHH; i += 256) {
        int h = i >> 6, d = i & 63;
        qs[h][d] = q[(((size_t)b * HH + h) * SS + qp) * DHH + d];
    }
    // --- load structure row (b,qp,:,:) f32 -> transposed bf16 LDS (R2 pattern) ---
    {
        const float* srow = structure + ((size_t)b * SS + qp) * (size_t)(SS * SDD);
        for (int k = tid; k < SS; k += 256) {
            const nfloat2* rp = (const nfloat2*)(srow + (size_t)k * SDD);
#pragma unroll
            for (int w = 0; w < 15; w++) {
                nfloat2 xv = __builtin_nontemporal_load(rp + w);
                stT[2 * w][k] = tobf(xv.x);
                stT[2 * w + 1][k] = tobf(xv.y);
            }
        }
    }
    __syncthreads();

    // --- qt[h][si] = qs[h] . Wsk[si]; qb[h] = qs[h] . bsk ---
    for (int i = tid; i < HH * SDD; i += 256) {
        int h = i / SDD, si = i % SDD;
        const float4* wp = (const float4*)(Wsk + si * DHH);
        const float4* qp4 = (const float4*)qs[h];
        float a = 0.f;
#pragma unroll
        for (int d4 = 0; d4 < 16; d4++) {
            float4 wv = wp[d4];
            float4 qv = qp4[d4];
            a += qv.x * wv.x + qv.y * wv.y + qv.z * wv.z + qv.w * wv.w;
        }
        qt_s[h][si] = a;
    }
    if (tid < HH) {
        const float4* bp = (const float4*)bsk;
        const float4* qp4 = (const float4*)qs[tid];
        float a = 0.f;
#pragma unroll
        for (int d4 = 0; d4 < 16; d4++) {
            float4 wv = bp[d4];
            float4 qv = qp4[d4];
            a += qv.x * wv.x + qv.y * wv.y + qv.z * wv.z + qv.w * wv.w;
        }
        qb_s[tid] = a;
    }
    __syncthreads();

    // --- scores: wave w -> heads 3w..3w+2, lane owns k = 8*lane..8*lane+7 ---
    int h0 = wave * 3;
    float attnv[3][8];
#pragma unroll
    for (int h = 0; h < 3; h++)
#pragma unroll
        for (int j = 0; j < 8; j++) attnv[h][j] = 0.f;

    // structure-score term: b128 reads of stT, broadcast qt
#pragma unroll 2
    for (int si = 0; si < SDD; si++) {
        uint4 sv4 = *(const uint4*)&stT[si][8 * lane];
        float t[8];
        unp8(sv4, t);
#pragma unroll
        for (int h = 0; h < 3; h++) {
            float qt = qt_s[h0 + h][si];
#pragma unroll
            for (int j = 0; j < 8; j++) attnv[h][j] += qt * t[j];
        }
    }

    // q.k term: bf16 kT, one uint4 = 8 k-values per d-row; fully coalesced
    {
        const unsigned short* kbase = kT + (((size_t)b * HH + h0) * DHH) * SS + 8 * lane;
#pragma unroll
        for (int h = 0; h < 3; h++) {
            const unsigned short* kp = kbase + (size_t)h * (DHH * SS);
            float acc[8] = {0.f, 0.f, 0.f, 0.f, 0.f, 0.f, 0.f, 0.f};
#pragma unroll 8
            for (int d = 0; d < DHH; d++) {
                float qd = qs[h0 + h][d];
                uint4 kv = *(const uint4*)(kp + (size_t)d * SS);
                float t[8];
                unp8(kv, t);
#pragma unroll
                for (int j = 0; j < 8; j++) acc[j] += qd * t[j];
            }
            float qb = qb_s[h0 + h];
#pragma unroll
            for (int j = 0; j < 8; j++) attnv[h][j] += acc[j] + qb;
        }
    }

    // mask
    {
        const int* mrow = mask + ((size_t)b * SS + qp) * SS + 8 * lane;
        nint4 m0v = __builtin_nontemporal_load((const nint4*)mrow);
        nint4 m1v = __builtin_nontemporal_load(((const nint4*)mrow) + 1);
        int mm[8] = {m0v.x, m0v.y, m0v.z, m0v.w, m1v.x, m1v.y, m1v.z, m1v.w};
#pragma unroll
        for (int h = 0; h < 3; h++)
#pragma unroll
            for (int j = 0; j < 8; j++)
                if (mm[j]) attnv[h][j] = -1e18f;
    }

    // --- softmax per head, in-wave ---
#pragma unroll
    for (int h = 0; h < 3; h++) {
        float m = attnv[h][0];
#pragma unroll
        for (int j = 1; j < 8; j++) m = fmaxf(m, attnv[h][j]);
#pragma unroll
        for (int off = 32; off > 0; off >>= 1) m = fmaxf(m, __shfl_xor(m, off));
        float l = 0.f;
#pragma unroll
        for (int j = 0; j < 8; j++) { attnv[h][j] = __expf(attnv[h][j] - m); l += attnv[h][j]; }
#pragma unroll
        for (int off = 32; off > 0; off >>= 1) l += __shfl_xor(l, off);
        float inv = 1.f / l;
        float a[8];
#pragma unroll
        for (int j = 0; j < 8; j++) a[j] = attnv[h][j] * inv;
        uint4 pk;
        pk.x = (uint32_ty)tobf(a[0]) | ((uint32_ty)tobf(a[1]) << 16);
        pk.y = (uint32_ty)tobf(a[2]) | ((uint32_ty)tobf(a[3]) << 16);
        pk.z = (uint32_ty)tobf(a[4]) | ((uint32_ty)tobf(a[5]) << 16);
        pk.w = (uint32_ty)tobf(a[6]) | ((uint32_ty)tobf(a[7]) << 16);
        *(uint4*)&at[h0 + h][8 * lane] = pk;
        if (h0 + h == 0) {
            float* tp = top_attn + ((size_t)b * SS + qp) * SS + 8 * lane;
            nfloat4 w0 = {a[0], a[1], a[2], a[3]};
            nfloat4 w1 = {a[4], a[5], a[6], a[7]};
            __builtin_nontemporal_store(w0, (nfloat4*)tp);
            __builtin_nontemporal_store(w1, ((nfloat4*)tp) + 1);
        }
    }
    __syncthreads();

    // --- astr[h][si] = sum_k attn[h][k] * structure[k][si] : all-b128 LDS ---
    if (tid < 180) {
        int h = tid / 15, sp = tid % 15;
        int si0 = 2 * sp, si1 = si0 + 1;
        float a0e = 0.f, a0o = 0.f, a1e = 0.f, a1o = 0.f;
#pragma unroll 2
        for (int j = 0; j < 64; j++) {
            uint4 av = *(const uint4*)&at[h][8 * j];
            uint4 s0 = *(const uint4*)&stT[si0][8 * j];
            uint4 s1 = *(const uint4*)&stT[si1][8 * j];
            float a[8], t0[8], t1[8];
            unp8(av, a); unp8(s0, t0); unp8(s1, t1);
#pragma unroll
            for (int t = 0; t < 8; t += 2) {
                a0e += a[t] * t0[t];     a0o += a[t + 1] * t0[t + 1];
                a1e += a[t] * t1[t];     a1o += a[t + 1] * t1[t + 1];
            }
        }
        astr_s[h][si0] = a0e + a0o;
        astr_s[h][si1] = a1e + a1o;
    }
    __syncthreads();

    // --- ctx: thread=(h, dq) computes 4 floats; attn@v (bf16 uint2 loads) + astr@Wsv + bsv ---
    if (tid < 192) {
        int h = tid >> 4, dq = tid & 15;
        const unsigned short* vp = v + ((size_t)b * HH + h) * (size_t)(SS * DHH) + 4 * dq;
        float4 ae; ae.x = ae.y = ae.z = ae.w = 0.f;
        float4 ao; ao.x = ao.y = ao.z = ao.w = 0.f;
#pragma unroll 2
        for (int j = 0; j < 64; j++) {
            uint4 av = *(const uint4*)&at[h][8 * j];
            float a[8];
            unp8(av, a);
            const unsigned short* vk = vp + (size_t)(8 * j) * DHH;
#pragma unroll
            for (int t = 0; t < 8; t += 2) {
                uint2 v0 = *(const uint2*)(vk + (size_t)t * DHH);
                uint2 v1 = *(const uint2*)(vk + (size_t)(t + 1) * DHH);
                float f0[4], f1[4];
                unp4(v0, f0); unp4(v1, f1);
                ae.x += a[t] * f0[0]; ae.y += a[t] * f0[1];
                ae.z += a[t] * f0[2]; ae.w += a[t] * f0[3];
                ao.x += a[t + 1] * f1[0]; ao.y += a[t + 1] * f1[1];
                ao.z += a[t + 1] * f1[2]; ao.w += a[t + 1] * f1[3];
            }
        }
        float4 sa = *(const float4*)(bsv + 4 * dq);
#pragma unroll
        for (int si = 0; si < SDD; si++) {
            float as = astr_s[h][si];
            float4 wv = *(const float4*)(Wsv + si * DHH + 4 * dq);
            sa.x += as * wv.x; sa.y += as * wv.y;
            sa.z += as * wv.z; sa.w += as * wv.w;
        }
        float4 outv;
        outv.x = ae.x + ao.x + sa.x;
        outv.y = ae.y + ao.y + sa.y;
        outv.z = ae.z + ao.z + sa.z;
        outv.w = ae.w + ao.w + sa.w;
        *(float4*)(ctx + ((size_t)b * SS + qp) * DD + h * DHH + 4 * dq) = outv;
    }
}

// ---------------------------------------------------------------------------
extern "C" void kernel_launch(void* const* d_in, const int* in_sizes, int n_in,
                              void* d_out, int out_size, void* d_ws, size_t ws_size,
                              hipStream_t stream)
{
    const float* key       = (const float*)d_in[0];
    const float* value     = (const float*)d_in[1];
    const float* query     = (const float*)d_in[2];
    const float* structure = (const float*)d_in[3];
    const int*   mask      = (const int*)d_in[4];
    const float* Wq  = (const float*)d_in[5];
    const float* bq  = (const float*)d_in[6];
    const float* Wk  = (const float*)d_in[7];
    const float* bk  = (const float*)d_in[8];
    const float* Wv  = (const float*)d_in[9];
    const float* bv  = (const float*)d_in[10];
    const float* Wsk = (const float*)d_in[11];
    const float* bsk = (const float*)d_in[12];
    const float* Wsv = (const float*)d_in[13];
    const float* bsv = (const float*)d_in[14];
    const float* Wo  = (const float*)d_in[15];
    const float* bo  = (const float*)d_in[16];

    float* out_main = (float*)d_out;                         // (B,S,D)
    float* out_attn = (float*)d_out + (size_t)BB * SS * DD;  // (B,S,S)

    float* ws = (float*)d_ws;
    float*          q_buf   = ws;                                  // (B,H,S,DH) f32
    unsigned short* kT_buf  = (unsigned short*)(ws + 1572864);     // (B,H,DH,S) bf16
    unsigned short* v_buf   = (unsigned short*)(ws + 2359296);     // (B,H,S,DH) bf16
    float*          ctx_buf = ws + 3145728;                        // (B,S,D) f32

    dim3 ggrd3(DD / MBN, (BB * SS) / MBM, 3);   // 12 x 32 x 3 = 1152 blocks
    gemm_proj3<<<ggrd3, dim3(256), 0, stream>>>(query, key, value, Wq, Wk, Wv,
                                                bq, bk, bv, q_buf, kT_buf, v_buf);

    attn_fused<<<BB * SS, 256, 0, stream>>>(q_buf, kT_buf, v_buf, structure, mask,
                                            Wsk, bsk, Wsv, bsv, ctx_buf, out_attn);

    dim3 ggrd(DD / TN, (BB * SS) / TM);         // 12 x 32
    gemm_out<<<ggrd, dim3(16, 16), 0, stream>>>(ctx_buf, Wo, bo, out_main);
}